// Round 4
// baseline (87.607 us; speedup 1.0000x reference)
//
#include <hip/hip_runtime.h>
#include <cmath>
#include <complex>
#include <algorithm>

// ---------------- compile-time path metadata ----------------
#define NPATH 15
constexpr int PL1[NPATH] = {0,0,0, 1,1,1,1,1,1, 2,2,2,2,2,2};
constexpr int PL2[NPATH] = {0,1,2, 0,1,1,1,2,2, 0,1,1,2,2,2};
constexpr int PL3[NPATH] = {0,1,2, 1,0,1,2,1,2, 2,1,2,0,1,2};
constexpr int CGOFF[NPATH] = {0,1,10,35,44,53,80,125,170,245,270,315,390,415,490};
constexpr int CGTOT = 615;
// yc layout: i-contiguous, stride per k = pad(d1) (1,4,8); bases 4-float aligned
constexpr int YB[NPATH]  = {0,4,8,16,28,32,44,64,76,96,136,160,200,208,232};
constexpr int PD1[NPATH] = {1,1,1,4,4,4,4,4,4,8,8,8,8,8,8};
constexpr int YCROW = 276;        // floats per row: 4-row stride -> distinct banks
constexpr int YOFF[3] = {0,1,4};
constexpr int KKB[3]  = {0,1,4};  // acc k-base per l3

struct CGArg { float v[CGTOT]; }; // alpha-folded real-basis CG (kernarg)

// ---------------- host: exact port of reference CG construction ----------------
static double factd(int n){ double r=1.0; for(int i=2;i<=n;++i) r*=(double)i; return r; }

static double su2_cg(int j1,int m1,int j2,int m2,int j3,int m3){
  if (m3 != m1+m2) return 0.0;
  double c = (double)(2*j3+1) * factd(j1+j2-j3) * factd(j1-j2+j3) * factd(-j1+j2+j3)
             / factd(j1+j2+j3+1);
  c = std::sqrt(c);
  c *= std::sqrt(factd(j3+m3)*factd(j3-m3)*factd(j1-m1)*factd(j1+m1)*factd(j2-m2)*factd(j2+m2));
  double s = 0.0;
  int kmin = std::max(0, std::max(j2-j3-m1, j1-j3+m2));
  int kmax = std::min(j1+j2-j3, std::min(j1-m1, j2+m2));
  for (int k=kmin;k<=kmax;++k){
    double d = factd(k)*factd(j1+j2-j3-k)*factd(j1-m1-k)*factd(j2+m2-k)
             * factd(j3-j2+m1+k)*factd(j3-j1-m2+k);
    s += ((k&1)? -1.0 : 1.0)/d;
  }
  return c*s;
}

static void qmat(int l, std::complex<double>* q){
  int d = 2*l+1;
  for (int a=0;a<d*d;++a) q[a] = std::complex<double>(0.0,0.0);
  const double r2 = 1.0/std::sqrt(2.0);
  for (int m=-l; m<0; ++m){
    q[(l+m)*d + (l-m)] = std::complex<double>(r2, 0.0);
    q[(l+m)*d + (l+m)] = std::complex<double>(0.0, -r2);
  }
  q[l*d + l] = std::complex<double>(1.0,0.0);
  for (int m=1; m<=l; ++m){
    double sg = (m&1)? -1.0 : 1.0;
    q[(l+m)*d + (l+m)] = std::complex<double>(sg*r2, 0.0);
    q[(l+m)*d + (l-m)] = std::complex<double>(0.0, sg*r2);
  }
  std::complex<double> ph = (l==0)? std::complex<double>(1,0)
                        : (l==1)? std::complex<double>(0,-1)
                                : std::complex<double>(-1,0);   // (-i)^l
  for (int a=0;a<d*d;++a) q[a] *= ph;
}

static void compute_cg(float* outv){
  const int npaths_to[3] = {3,6,6};
  for (int p=0;p<NPATH;++p){
    int l1=PL1[p], l2=PL2[p], l3=PL3[p];
    int d1=2*l1+1, d2=2*l2+1, d3=2*l3+1;
    std::complex<double> C[5][5][5];
    for (int a=0;a<5;++a) for(int b=0;b<5;++b) for(int c=0;c<5;++c) C[a][b][c]=std::complex<double>(0,0);
    for (int m1=-l1;m1<=l1;++m1) for (int m2=-l2;m2<=l2;++m2){
      int m3=m1+m2;
      if (std::abs(m3)<=l3) C[l1+m1][l2+m2][l3+m3] = su2_cg(l1,m1,l2,m2,l3,m3);
    }
    std::complex<double> U1[25],U2[25],U3[25];
    qmat(l1,U1); qmat(l2,U2); qmat(l3,U3);
    double Cr[5][5][5]; double nrm=0.0;
    for (int a=0;a<d1;++a) for (int b=0;b<d2;++b) for (int c=0;c<d3;++c){
      std::complex<double> s(0,0);
      for (int i=0;i<d1;++i) for (int j=0;j<d2;++j) for (int k=0;k<d3;++k)
        s += U1[i*d1+a]*U2[j*d2+b]*std::conj(U3[k*d3+c])*C[i][j][k];
      Cr[a][b][c] = s.real();
      nrm += s.real()*s.real();
    }
    nrm = std::sqrt(nrm);
    double alpha = 1.0/std::sqrt(64.0*(double)npaths_to[l3]);
    float* o = outv + CGOFF[p];
    int idx=0;
    for (int a=0;a<d1;++a) for (int b=0;b<d2;++b) for (int c=0;c<d3;++c)
      o[idx++] = (float)(Cr[a][b][c]/nrm*alpha);
  }
}

// ---------------- device ----------------
typedef short bf16x8 __attribute__((ext_vector_type(8)));
typedef float f32x4 __attribute__((ext_vector_type(4)));

__device__ __forceinline__ unsigned cvtpk_bf16(float a, float b){
  unsigned r;
  asm("v_cvt_pk_bf16_f32 %0, %1, %2" : "=v"(r) : "v"(a), "v"(b));
  return r;   // lo16 = bf16(a), hi16 = bf16(b)
}

// A-fragment: lane (cl,q) holds A[row=cl][u=kt*32+q*8 ..+7]; XOR-swizzled 16B chunks (R2-verified)
__device__ __forceinline__ bf16x8 afrag(const unsigned short* s_xt, int plane, int kt, int row, int q){
  int c = (kt*4 + q) ^ (row & 7);
  return *reinterpret_cast<const bf16x8*>(s_xt + (plane*16 + row)*64 + c*8);
}
// B-fragment: lane (cl,q) holds B[u=kt*32+q*8..+7][w=wt*16+cl] from WT[p][w][u]
__device__ __forceinline__ bf16x8 wfrag(const unsigned short* WT, int p, int wt, int cl, int kt, int q){
  return *reinterpret_cast<const bf16x8*>(WT + p*4096 + (wt*16+cl)*64 + kt*32 + q*8);
}
// xT write of one packed u-quad (swizzle matches afrag)
__device__ __forceinline__ void xt_write_pk(unsigned short* s_xt, int plane, int n, int t16, uint2 pk){
  const int swz = (((t16>>1)^(n&7))<<3) + ((t16&1)<<2);
  *reinterpret_cast<uint2*>(s_xt + (plane*16 + n)*64 + swz) = pk;
}

// pack this thread's x registers (f32) into 9 packed bf16 u-quads (one per plane)
__device__ __forceinline__ void pack_x(const float4& r0, const float4* r1, const float4* r2, uint2* xpk){
  const float* f0 = reinterpret_cast<const float*>(&r0);   // 4:  x[t16*4+uu]
  const float* f1 = reinterpret_cast<const float*>(r1);    // 12: x[64 + (4t16+uu)*3 + i]
  const float* f2 = reinterpret_cast<const float*>(r2);    // 20: x[256 + (4t16+uu)*5 + i]
  xpk[0].x = cvtpk_bf16(f0[0], f0[1]);  xpk[0].y = cvtpk_bf16(f0[2], f0[3]);
  #pragma unroll
  for (int i=0;i<3;++i){
    xpk[1+i].x = cvtpk_bf16(f1[0*3+i], f1[1*3+i]);
    xpk[1+i].y = cvtpk_bf16(f1[2*3+i], f1[3*3+i]);
  }
  #pragma unroll
  for (int i=0;i<5;++i){
    xpk[4+i].x = cvtpk_bf16(f2[0*5+i], f2[1*5+i]);
    xpk[4+i].y = cvtpk_bf16(f2[2*5+i], f2[3*5+i]);
  }
}

__device__ __forceinline__ void yc_compute(const float (*s_y)[9], float* s_yc,
                                           const CGArg& cga, int tid){
  #pragma unroll
  for (int p=0;p<NPATH;++p){
    const int d1=2*PL1[p]+1, d2=2*PL2[p]+1, d3=2*PL3[p]+1;
    const int cnt = 16*d1*d3;
    for (int idx=tid; idx<cnt; idx+=256){
      int n = idx/(d1*d3);
      int r = idx - n*(d1*d3);
      int i = r/d3;
      int k = r - i*d3;
      float s=0.f;
      for (int j=0;j<d2;++j)
        s += s_y[n][YOFF[PL2[p]]+j]*cga.v[CGOFF[p]+(i*d2+j)*d3+k];
      s_yc[n*YCROW + YB[p] + k*PD1[p] + i] = s;
    }
  }
}

// path compute with pre-loaded B fragments; a-frags in registers (L1 in {0,1})
template<int P,int L1,int L3>
__device__ __forceinline__ void compute_path(bf16x8 b0, bf16x8 b1, const bf16x8* a,
                                             const float* ycq, f32x4* acc){
  constexpr int D1=2*L1+1, D3=2*L3+1, PD=PD1[P];
  const f32x4 z4 = {0.f,0.f,0.f,0.f};
  f32x4 T[D1];
  #pragma unroll
  for (int i=0;i<D1;++i){
    T[i] = __builtin_amdgcn_mfma_f32_16x16x32_bf16(a[2*i],   b0, z4,  0,0,0);
    T[i] = __builtin_amdgcn_mfma_f32_16x16x32_bf16(a[2*i+1], b1, T[i],0,0,0);
  }
  #pragma unroll
  for (int r=0;r<4;++r){
    const float* yr = ycq + r*YCROW + YB[P];
    #pragma unroll
    for (int k=0;k<D3;++k){
      const float* ya = yr + k*PD;
      if constexpr (D1==1){
        acc[KKB[L3]+k][r] += T[0][r]*ya[0];
      } else {
        float4 yv = *reinterpret_cast<const float4*>(ya);
        acc[KKB[L3]+k][r] += T[0][r]*yv.x + T[1][r]*yv.y + T[2][r]*yv.z;
      }
    }
  }
}

// L1==2 variant: a-frags re-read from LDS per path (saves 40 VGPRs of live range)
template<int P,int L3>
__device__ __forceinline__ void compute_path_l2(bf16x8 b0, bf16x8 b1,
                                                const unsigned short* s_xt,
                                                const float* ycq, f32x4* acc,
                                                int cl, int q){
  constexpr int D3=2*L3+1, PD=PD1[P];
  const f32x4 z4 = {0.f,0.f,0.f,0.f};
  f32x4 T[5];
  #pragma unroll
  for (int i=0;i<5;++i){
    bf16x8 a0 = afrag(s_xt, 4+i, 0, cl, q);
    bf16x8 a1 = afrag(s_xt, 4+i, 1, cl, q);
    T[i] = __builtin_amdgcn_mfma_f32_16x16x32_bf16(a0, b0, z4,  0,0,0);
    T[i] = __builtin_amdgcn_mfma_f32_16x16x32_bf16(a1, b1, T[i],0,0,0);
  }
  #pragma unroll
  for (int r=0;r<4;++r){
    const float* yr = ycq + r*YCROW + YB[P];
    #pragma unroll
    for (int k=0;k<D3;++k){
      const float* ya = yr + k*PD;
      float4 yv = *reinterpret_cast<const float4*>(ya);
      float y4 = ya[4];
      acc[KKB[L3]+k][r] += T[0][r]*yv.x + T[1][r]*yv.y + T[2][r]*yv.z
                         + T[3][r]*yv.w + T[4][r]*y4;
    }
  }
}

__device__ __forceinline__ void epilogue(const f32x4* acc, float* __restrict__ out,
                                         int base, int wid, int cl, int q){
  const int wc = wid*16 + cl;
  #pragma unroll
  for (int r=0;r<4;++r){
    float* orow = out + (size_t)(base + q*4 + r)*576;
    orow[wc] = acc[0][r];
    #pragma unroll
    for (int k=0;k<3;++k) orow[64 + wc*3 + k]  = acc[1+k][r];
    #pragma unroll
    for (int k=0;k<5;++k) orow[256 + wc*5 + k] = acc[4+k][r];
  }
}

__global__ __launch_bounds__(256, 4)
void tp_kernel(const float* __restrict__ x, const float* __restrict__ y,
               const unsigned short* __restrict__ WT, float* __restrict__ out, CGArg cga)
{
  __shared__ __align__(16) unsigned short s_xt[9*16*64];  // 18432 B
  __shared__ float s_yc[16*YCROW];                        // 17664 B
  __shared__ float s_y[16][9];

  const int tid = threadIdx.x;
  const int n0 = blockIdx.x * 32;      // this block owns rows n0..n0+31 (2 tiles)
  const int n_s = tid>>4, t16 = tid&15;
  const int lane = tid & 63, wid = tid >> 6;
  const int cl = lane & 15, q = lane >> 4;
  const float* ycq = s_yc + q*4*YCROW;
  const int ynl = tid/9, yj = tid - ynl*9;   // y-load mapping (tid<144)

  // ---- tile-0 loads (cold) ----
  const float* xb0 = x + (size_t)(n0 + n_s)*576;
  float4 r0 = *reinterpret_cast<const float4*>(xb0 + t16*4);
  float4 r1[3], r2[5];
  #pragma unroll
  for (int i=0;i<3;++i) r1[i] = *reinterpret_cast<const float4*>(xb0 + 64 + t16*12 + 4*i);
  #pragma unroll
  for (int i=0;i<5;++i) r2[i] = *reinterpret_cast<const float4*>(xb0 + 256 + t16*20 + 4*i);
  float yreg = (tid<144) ? y[(size_t)(n0+ynl)*9 + yj] : 0.f;
  uint2 xpkA[9];
  pack_x(r0, r1, r2, xpkA);

  const f32x4 z4 = {0.f,0.f,0.f,0.f};
  uint2 xpkB[9];
  float yreg1 = 0.f;

  #define LDB(P) { nb0 = wfrag(WT,P,wid,cl,0,q); nb1 = wfrag(WT,P,wid,cl,1,q); }
  #define ADV    { b0 = nb0; b1 = nb1; }

  // ================= TILE 0 =================
  if (tid < 144) s_y[ynl][yj] = yreg;
  #pragma unroll
  for (int pl=0; pl<9; ++pl) xt_write_pk(s_xt, pl, n_s, t16, xpkA[pl]);
  __syncthreads();
  yc_compute(s_y, s_yc, cga, tid);
  __syncthreads();

  {
    // prefetch tile-1 x/y: issue now, consume after l1=1 group (latency hidden)
    const float* xb1 = xb0 + 16*576;
    float4 p0 = *reinterpret_cast<const float4*>(xb1 + t16*4);
    float4 p1[3], p2[5];
    #pragma unroll
    for (int i=0;i<3;++i) p1[i] = *reinterpret_cast<const float4*>(xb1 + 64 + t16*12 + 4*i);
    #pragma unroll
    for (int i=0;i<5;++i) p2[i] = *reinterpret_cast<const float4*>(xb1 + 256 + t16*20 + 4*i);
    if (tid < 144) yreg1 = y[(size_t)(n0+16+ynl)*9 + yj];

    f32x4 acc[9] = {z4,z4,z4,z4,z4,z4,z4,z4,z4};
    bf16x8 b0,b1,nb0,nb1;
    bf16x8 a0[2];
    #pragma unroll
    for (int kt=0;kt<2;++kt) a0[kt] = afrag(s_xt, 0, kt, cl, q);
    b0 = wfrag(WT,0,wid,cl,0,q); b1 = wfrag(WT,0,wid,cl,1,q);

    LDB(1);  compute_path<0,0,0>(b0,b1,a0,ycq,acc); ADV;
    LDB(2);  compute_path<1,0,1>(b0,b1,a0,ycq,acc); ADV;
    bf16x8 a1[6];
    #pragma unroll
    for (int i=0;i<3;++i)
      #pragma unroll
      for (int kt=0;kt<2;++kt) a1[2*i+kt] = afrag(s_xt, 1+i, kt, cl, q);
    LDB(3);  compute_path<2,0,2>(b0,b1,a0,ycq,acc); ADV;
    LDB(4);  compute_path<3,1,1>(b0,b1,a1,ycq,acc); ADV;
    LDB(5);  compute_path<4,1,0>(b0,b1,a1,ycq,acc); ADV;
    LDB(6);  compute_path<5,1,1>(b0,b1,a1,ycq,acc); ADV;
    pack_x(p0, p1, p2, xpkB);           // f32 prefetch regs die here
    LDB(7);  compute_path<6,1,2>(b0,b1,a1,ycq,acc); ADV;
    LDB(8);  compute_path<7,1,1>(b0,b1,a1,ycq,acc); ADV;
    LDB(9);  compute_path<8,1,2>(b0,b1,a1,ycq,acc); ADV;
    LDB(10); compute_path_l2<9,2>(b0,b1,s_xt,ycq,acc,cl,q); ADV;
    LDB(11); compute_path_l2<10,1>(b0,b1,s_xt,ycq,acc,cl,q); ADV;
    LDB(12); compute_path_l2<11,2>(b0,b1,s_xt,ycq,acc,cl,q); ADV;
    LDB(13); compute_path_l2<12,0>(b0,b1,s_xt,ycq,acc,cl,q); ADV;
    LDB(14); compute_path_l2<13,1>(b0,b1,s_xt,ycq,acc,cl,q); ADV;
             compute_path_l2<14,2>(b0,b1,s_xt,ycq,acc,cl,q);

    epilogue(acc, out, n0, wid, cl, q);
  }

  __syncthreads();   // all waves done reading s_xt/s_yc of tile 0

  // ================= TILE 1 =================
  if (tid < 144) s_y[ynl][yj] = yreg1;
  #pragma unroll
  for (int pl=0; pl<9; ++pl) xt_write_pk(s_xt, pl, n_s, t16, xpkB[pl]);
  __syncthreads();
  yc_compute(s_y, s_yc, cga, tid);
  __syncthreads();

  {
    f32x4 acc[9] = {z4,z4,z4,z4,z4,z4,z4,z4,z4};
    bf16x8 b0,b1,nb0,nb1;
    bf16x8 a0[2];
    #pragma unroll
    for (int kt=0;kt<2;++kt) a0[kt] = afrag(s_xt, 0, kt, cl, q);
    b0 = wfrag(WT,0,wid,cl,0,q); b1 = wfrag(WT,0,wid,cl,1,q);

    LDB(1);  compute_path<0,0,0>(b0,b1,a0,ycq,acc); ADV;
    LDB(2);  compute_path<1,0,1>(b0,b1,a0,ycq,acc); ADV;
    bf16x8 a1[6];
    #pragma unroll
    for (int i=0;i<3;++i)
      #pragma unroll
      for (int kt=0;kt<2;++kt) a1[2*i+kt] = afrag(s_xt, 1+i, kt, cl, q);
    LDB(3);  compute_path<2,0,2>(b0,b1,a0,ycq,acc); ADV;
    LDB(4);  compute_path<3,1,1>(b0,b1,a1,ycq,acc); ADV;
    LDB(5);  compute_path<4,1,0>(b0,b1,a1,ycq,acc); ADV;
    LDB(6);  compute_path<5,1,1>(b0,b1,a1,ycq,acc); ADV;
    LDB(7);  compute_path<6,1,2>(b0,b1,a1,ycq,acc); ADV;
    LDB(8);  compute_path<7,1,1>(b0,b1,a1,ycq,acc); ADV;
    LDB(9);  compute_path<8,1,2>(b0,b1,a1,ycq,acc); ADV;
    LDB(10); compute_path_l2<9,2>(b0,b1,s_xt,ycq,acc,cl,q); ADV;
    LDB(11); compute_path_l2<10,1>(b0,b1,s_xt,ycq,acc,cl,q); ADV;
    LDB(12); compute_path_l2<11,2>(b0,b1,s_xt,ycq,acc,cl,q); ADV;
    LDB(13); compute_path_l2<12,0>(b0,b1,s_xt,ycq,acc,cl,q); ADV;
    LDB(14); compute_path_l2<13,1>(b0,b1,s_xt,ycq,acc,cl,q); ADV;
             compute_path_l2<14,2>(b0,b1,s_xt,ycq,acc,cl,q);

    epilogue(acc, out, n0+16, wid, cl, q);
  }
  #undef LDB
  #undef ADV
}

// W[p][u][w] (fp32) -> WT[p][w][u] (bf16, RNE) once per launch
__global__ void wt_kernel(const float* __restrict__ W, unsigned short* __restrict__ WT){
  int t = blockIdx.x*256 + threadIdx.x;      // 61440 total
  int p = t >> 12, r = t & 4095, w = r >> 6, u = r & 63;
  float f = W[(p<<12) + (u<<6) + w];
  unsigned fu = __builtin_bit_cast(unsigned, f);
  unsigned rr = (fu + 0x7FFFu + ((fu>>16)&1u)) >> 16;
  WT[t] = (unsigned short)rr;
}

// ---------------- launch ----------------
extern "C" void kernel_launch(void* const* d_in, const int* in_sizes, int n_in,
                              void* d_out, int out_size, void* d_ws, size_t ws_size,
                              hipStream_t stream) {
  const float* x = (const float*)d_in[0];
  const float* y = (const float*)d_in[1];
  const float* W = (const float*)d_in[2];
  float* out = (float*)d_out;
  (void)in_sizes; (void)n_in; (void)out_size; (void)ws_size;

  unsigned short* WT = (unsigned short*)d_ws;   // 61440 * 2 B

  CGArg cga;
  compute_cg(cga.v);

  hipLaunchKernelGGL(wt_kernel, dim3(240), dim3(256), 0, stream, W, WT);
  hipLaunchKernelGGL(tp_kernel, dim3(1024), dim3(256), 0, stream, x, y, WT, out, cga);
}

// Round 5
// 76.289 us; speedup vs baseline: 1.1484x; 1.1484x over previous
//
#include <hip/hip_runtime.h>
#include <cmath>
#include <complex>
#include <algorithm>

// ---------------- compile-time path metadata ----------------
#define NPATH 15
constexpr int PL1[NPATH] = {0,0,0, 1,1,1,1,1,1, 2,2,2,2,2,2};
constexpr int PL2[NPATH] = {0,1,2, 0,1,1,1,2,2, 0,1,1,2,2,2};
constexpr int PL3[NPATH] = {0,1,2, 1,0,1,2,1,2, 2,1,2,0,1,2};
constexpr int CGOFF[NPATH] = {0,1,10,35,44,53,80,125,170,245,270,315,390,415,490};
constexpr int CGTOT = 615;
// yc2 layout: [(YB2[p] + i*D3 + k)*16 + n] — n fastest (16 rows), broadcast-read as f32x4 over r
constexpr int YB2[NPATH] = {0,1,4,9,18,21,30,45,54,69,94,109,134,139,154};  // cumsum of D1*D3
constexpr int YC2TOT = 179;
constexpr int YOFF[3] = {0,1,4};
constexpr int KKB[3]  = {0,1,4};  // acc k-base per l3

struct CGArg { float v[CGTOT]; }; // alpha-folded real-basis CG (kernarg)

// ---------------- host: exact port of reference CG construction ----------------
static double factd(int n){ double r=1.0; for(int i=2;i<=n;++i) r*=(double)i; return r; }

static double su2_cg(int j1,int m1,int j2,int m2,int j3,int m3){
  if (m3 != m1+m2) return 0.0;
  double c = (double)(2*j3+1) * factd(j1+j2-j3) * factd(j1-j2+j3) * factd(-j1+j2+j3)
             / factd(j1+j2+j3+1);
  c = std::sqrt(c);
  c *= std::sqrt(factd(j3+m3)*factd(j3-m3)*factd(j1-m1)*factd(j1+m1)*factd(j2-m2)*factd(j2+m2));
  double s = 0.0;
  int kmin = std::max(0, std::max(j2-j3-m1, j1-j3+m2));
  int kmax = std::min(j1+j2-j3, std::min(j1-m1, j2+m2));
  for (int k=kmin;k<=kmax;++k){
    double d = factd(k)*factd(j1+j2-j3-k)*factd(j1-m1-k)*factd(j2+m2-k)
             * factd(j3-j2+m1+k)*factd(j3-j1-m2+k);
    s += ((k&1)? -1.0 : 1.0)/d;
  }
  return c*s;
}

static void qmat(int l, std::complex<double>* q){
  int d = 2*l+1;
  for (int a=0;a<d*d;++a) q[a] = std::complex<double>(0.0,0.0);
  const double r2 = 1.0/std::sqrt(2.0);
  for (int m=-l; m<0; ++m){
    q[(l+m)*d + (l-m)] = std::complex<double>(r2, 0.0);
    q[(l+m)*d + (l+m)] = std::complex<double>(0.0, -r2);
  }
  q[l*d + l] = std::complex<double>(1.0,0.0);
  for (int m=1; m<=l; ++m){
    double sg = (m&1)? -1.0 : 1.0;
    q[(l+m)*d + (l+m)] = std::complex<double>(sg*r2, 0.0);
    q[(l+m)*d + (l-m)] = std::complex<double>(0.0, sg*r2);
  }
  std::complex<double> ph = (l==0)? std::complex<double>(1,0)
                        : (l==1)? std::complex<double>(0,-1)
                                : std::complex<double>(-1,0);   // (-i)^l
  for (int a=0;a<d*d;++a) q[a] *= ph;
}

static void compute_cg(float* outv){
  const int npaths_to[3] = {3,6,6};
  for (int p=0;p<NPATH;++p){
    int l1=PL1[p], l2=PL2[p], l3=PL3[p];
    int d1=2*l1+1, d2=2*l2+1, d3=2*l3+1;
    std::complex<double> C[5][5][5];
    for (int a=0;a<5;++a) for(int b=0;b<5;++b) for(int c=0;c<5;++c) C[a][b][c]=std::complex<double>(0,0);
    for (int m1=-l1;m1<=l1;++m1) for (int m2=-l2;m2<=l2;++m2){
      int m3=m1+m2;
      if (std::abs(m3)<=l3) C[l1+m1][l2+m2][l3+m3] = su2_cg(l1,m1,l2,m2,l3,m3);
    }
    std::complex<double> U1[25],U2[25],U3[25];
    qmat(l1,U1); qmat(l2,U2); qmat(l3,U3);
    double Cr[5][5][5]; double nrm=0.0;
    for (int a=0;a<d1;++a) for (int b=0;b<d2;++b) for (int c=0;c<d3;++c){
      std::complex<double> s(0,0);
      for (int i=0;i<d1;++i) for (int j=0;j<d2;++j) for (int k=0;k<d3;++k)
        s += U1[i*d1+a]*U2[j*d2+b]*std::conj(U3[k*d3+c])*C[i][j][k];
      Cr[a][b][c] = s.real();
      nrm += s.real()*s.real();
    }
    nrm = std::sqrt(nrm);
    double alpha = 1.0/std::sqrt(64.0*(double)npaths_to[l3]);
    float* o = outv + CGOFF[p];
    int idx=0;
    for (int a=0;a<d1;++a) for (int b=0;b<d2;++b) for (int c=0;c<d3;++c)
      o[idx++] = (float)(Cr[a][b][c]/nrm*alpha);
  }
}

// ---------------- device ----------------
typedef short bf16x8 __attribute__((ext_vector_type(8)));
typedef float f32x4 __attribute__((ext_vector_type(4)));

__device__ __forceinline__ unsigned cvtpk_bf16(float a, float b){
  unsigned r;
  asm("v_cvt_pk_bf16_f32 %0, %1, %2" : "=v"(r) : "v"(a), "v"(b));
  return r;   // lo16 = bf16(a), hi16 = bf16(b)
}

// A-fragment: lane (cl,q) holds A[row=cl][u=kt*32+q*8 ..+7]; XOR-swizzled 16B chunks (R2-verified)
__device__ __forceinline__ bf16x8 afrag(const unsigned short* s_xt, int plane, int kt, int row, int q){
  int c = (kt*4 + q) ^ (row & 7);
  return *reinterpret_cast<const bf16x8*>(s_xt + (plane*16 + row)*64 + c*8);
}
// B-fragment: lane (cl,q) holds B[u=kt*32+q*8..+7][w=wt*16+cl] from WT[p][w][u]
__device__ __forceinline__ bf16x8 wfrag(const unsigned short* WT, int p, int wt, int cl, int kt, int q){
  return *reinterpret_cast<const bf16x8*>(WT + p*4096 + (wt*16+cl)*64 + kt*32 + q*8);
}
// xT write of one packed u-quad (swizzle matches afrag)
__device__ __forceinline__ void xt_write_pk(unsigned short* s_xt, int plane, int n, int t16, uint2 pk){
  const int swz = (((t16>>1)^(n&7))<<3) + ((t16&1)<<2);
  *reinterpret_cast<uint2*>(s_xt + (plane*16 + n)*64 + swz) = pk;
}

// pack this thread's x registers (f32) into 9 packed bf16 u-quads (one per plane)
__device__ __forceinline__ void pack_x(const float4& r0, const float4* r1, const float4* r2, uint2* xpk){
  const float* f0 = reinterpret_cast<const float*>(&r0);   // 4:  x[t16*4+uu]
  const float* f1 = reinterpret_cast<const float*>(r1);    // 12: x[64 + (4t16+uu)*3 + i]
  const float* f2 = reinterpret_cast<const float*>(r2);    // 20: x[256 + (4t16+uu)*5 + i]
  xpk[0].x = cvtpk_bf16(f0[0], f0[1]);  xpk[0].y = cvtpk_bf16(f0[2], f0[3]);
  #pragma unroll
  for (int i=0;i<3;++i){
    xpk[1+i].x = cvtpk_bf16(f1[0*3+i], f1[1*3+i]);
    xpk[1+i].y = cvtpk_bf16(f1[2*3+i], f1[3*3+i]);
  }
  #pragma unroll
  for (int i=0;i<5;++i){
    xpk[4+i].x = cvtpk_bf16(f2[0*5+i], f2[1*5+i]);
    xpk[4+i].y = cvtpk_bf16(f2[2*5+i], f2[3*5+i]);
  }
}

// yc2[(YB2[p] + i*D3 + k)*16 + n] = sum_j y[n][j]*cg[p][i][j][k]  (alpha folded)
// n fastest across tids -> conflict-free LDS writes
__device__ __forceinline__ void yc_compute(const float (*s_y)[9], float* s_yc2,
                                           const CGArg& cga, int tid){
  #pragma unroll
  for (int p=0;p<NPATH;++p){
    const int d1=2*PL1[p]+1, d2=2*PL2[p]+1, d3=2*PL3[p]+1;
    const int cnt = d1*d3*16;
    for (int idx=tid; idx<cnt; idx+=256){
      int n  = idx & 15;
      int ik = idx >> 4;
      int i  = ik/d3;
      int k  = ik - i*d3;
      float s=0.f;
      for (int j=0;j<d2;++j)
        s += s_y[n][YOFF[PL2[p]]+j]*cga.v[CGOFF[p]+(i*d2+j)*d3+k];
      s_yc2[(YB2[p]+ik)*16 + n] = s;
    }
  }
}

// issue path P's MFMAs into T (a-frags from LDS; b preloaded)
template<int P,int L1>
__device__ __forceinline__ void issue_path(const unsigned short* s_xt, bf16x8 b0, bf16x8 b1,
                                           f32x4* T, int cl, int q){
  constexpr int D1=2*L1+1;
  constexpr int PB = (L1==0)?0:(L1==1)?1:4;
  const f32x4 z4 = {0.f,0.f,0.f,0.f};
  #pragma unroll
  for (int i=0;i<D1;++i){
    bf16x8 a0 = afrag(s_xt, PB+i, 0, cl, q);
    bf16x8 a1 = afrag(s_xt, PB+i, 1, cl, q);
    T[i] = __builtin_amdgcn_mfma_f32_16x16x32_bf16(a0, b0, z4,  0,0,0);
    T[i] = __builtin_amdgcn_mfma_f32_16x16x32_bf16(a1, b1, T[i],0,0,0);
  }
}

// consume path P's T: acc[k] += T[i] * yc2_vec  (packed f32x4 over the 4 r-rows)
template<int P,int L3,int D1>
__device__ __forceinline__ void consume_path(const f32x4* T, const float* s_yc2,
                                             f32x4* acc, int q){
  constexpr int D3=2*L3+1;
  const float* yb = s_yc2 + YB2[P]*16 + q*4;
  #pragma unroll
  for (int i=0;i<D1;++i)
    #pragma unroll
    for (int k=0;k<D3;++k){
      f32x4 yv = *reinterpret_cast<const f32x4*>(yb + (i*D3+k)*16);
      acc[KKB[L3]+k] += T[i]*yv;
    }
}

__device__ __forceinline__ void epilogue(const f32x4* acc, float* __restrict__ out,
                                         int base, int wid, int cl, int q){
  const int wc = wid*16 + cl;
  #pragma unroll
  for (int r=0;r<4;++r){
    float* orow = out + (size_t)(base + q*4 + r)*576;
    orow[wc] = acc[0][r];
    #pragma unroll
    for (int k=0;k<3;++k) orow[64 + wc*3 + k]  = acc[1+k][r];
    #pragma unroll
    for (int k=0;k<5;++k) orow[256 + wc*5 + k] = acc[4+k][r];
  }
}

__global__ __launch_bounds__(256, 4)
void tp_kernel(const float* __restrict__ x, const float* __restrict__ y,
               const unsigned short* __restrict__ WT, float* __restrict__ out, CGArg cga)
{
  __shared__ __align__(16) unsigned short s_xt[9*16*64];  // 18432 B
  __shared__ __align__(16) float s_yc2[YC2TOT*16];        // 11456 B
  __shared__ float s_y[16][9];

  const int tid = threadIdx.x;
  const int n0 = blockIdx.x * 16;
  const int n_s = tid>>4, t16 = tid&15;
  const int lane = tid & 63, wid = tid >> 6;
  const int cl = lane & 15, q = lane >> 4;

  // ---- loads ----
  const float* xb = x + (size_t)(n0 + n_s)*576;
  float4 r0 = *reinterpret_cast<const float4*>(xb + t16*4);
  float4 r1[3], r2[5];
  #pragma unroll
  for (int i=0;i<3;++i) r1[i] = *reinterpret_cast<const float4*>(xb + 64 + t16*12 + 4*i);
  #pragma unroll
  for (int i=0;i<5;++i) r2[i] = *reinterpret_cast<const float4*>(xb + 256 + t16*20 + 4*i);
  if (tid < 144){
    int ynl = tid/9, yj = tid - ynl*9;
    s_y[ynl][yj] = y[(size_t)(n0+ynl)*9 + yj];
  }

  uint2 xpk[9];
  pack_x(r0, r1, r2, xpk);
  #pragma unroll
  for (int pl=0; pl<9; ++pl) xt_write_pk(s_xt, pl, n_s, t16, xpk[pl]);
  __syncthreads();
  yc_compute(s_y, s_yc2, cga, tid);
  __syncthreads();

  const f32x4 z4 = {0.f,0.f,0.f,0.f};
  f32x4 acc[9] = {z4,z4,z4,z4,z4,z4,z4,z4,z4};   // k: 0 | 1..3 | 4..8
  f32x4 TA[5], TB[5];
  bf16x8 b0,b1,nb0,nb1;

  #define LDB(P) { nb0 = wfrag(WT,P,wid,cl,0,q); nb1 = wfrag(WT,P,wid,cl,1,q); }
  #define ADV    { b0 = nb0; b1 = nb1; }

  b0 = wfrag(WT,0,wid,cl,0,q); b1 = wfrag(WT,0,wid,cl,1,q);

  // deferred-T pipeline: issue path p, consume path p-1 while MFMAs complete
  LDB(1);  issue_path<0,0>(s_xt,b0,b1,TA,cl,q);                                   ADV;
  LDB(2);  issue_path<1,0>(s_xt,b0,b1,TB,cl,q); consume_path<0,0,1>(TA,s_yc2,acc,q); ADV;
  LDB(3);  issue_path<2,0>(s_xt,b0,b1,TA,cl,q); consume_path<1,1,1>(TB,s_yc2,acc,q); ADV;
  LDB(4);  issue_path<3,1>(s_xt,b0,b1,TB,cl,q); consume_path<2,2,1>(TA,s_yc2,acc,q); ADV;
  LDB(5);  issue_path<4,1>(s_xt,b0,b1,TA,cl,q); consume_path<3,1,3>(TB,s_yc2,acc,q); ADV;
  LDB(6);  issue_path<5,1>(s_xt,b0,b1,TB,cl,q); consume_path<4,0,3>(TA,s_yc2,acc,q); ADV;
  LDB(7);  issue_path<6,1>(s_xt,b0,b1,TA,cl,q); consume_path<5,1,3>(TB,s_yc2,acc,q); ADV;
  LDB(8);  issue_path<7,1>(s_xt,b0,b1,TB,cl,q); consume_path<6,2,3>(TA,s_yc2,acc,q); ADV;
  LDB(9);  issue_path<8,1>(s_xt,b0,b1,TA,cl,q); consume_path<7,1,3>(TB,s_yc2,acc,q); ADV;
  LDB(10); issue_path<9,2>(s_xt,b0,b1,TB,cl,q); consume_path<8,2,3>(TA,s_yc2,acc,q); ADV;
  LDB(11); issue_path<10,2>(s_xt,b0,b1,TA,cl,q); consume_path<9,2,5>(TB,s_yc2,acc,q); ADV;
  LDB(12); issue_path<11,2>(s_xt,b0,b1,TB,cl,q); consume_path<10,1,5>(TA,s_yc2,acc,q); ADV;
  LDB(13); issue_path<12,2>(s_xt,b0,b1,TA,cl,q); consume_path<11,2,5>(TB,s_yc2,acc,q); ADV;
  LDB(14); issue_path<13,2>(s_xt,b0,b1,TB,cl,q); consume_path<12,0,5>(TA,s_yc2,acc,q); ADV;
           issue_path<14,2>(s_xt,b0,b1,TA,cl,q); consume_path<13,1,5>(TB,s_yc2,acc,q);
                                                 consume_path<14,2,5>(TA,s_yc2,acc,q);
  #undef LDB
  #undef ADV

  epilogue(acc, out, n0, wid, cl, q);
}

// W[p][u][w] (fp32) -> WT[p][w][u] (bf16, RNE) once per launch
__global__ void wt_kernel(const float* __restrict__ W, unsigned short* __restrict__ WT){
  int t = blockIdx.x*256 + threadIdx.x;      // 61440 total
  int p = t >> 12, r = t & 4095, w = r >> 6, u = r & 63;
  float f = W[(p<<12) + (u<<6) + w];
  unsigned fu = __builtin_bit_cast(unsigned, f);
  unsigned rr = (fu + 0x7FFFu + ((fu>>16)&1u)) >> 16;
  WT[t] = (unsigned short)rr;
}

// ---------------- launch ----------------
extern "C" void kernel_launch(void* const* d_in, const int* in_sizes, int n_in,
                              void* d_out, int out_size, void* d_ws, size_t ws_size,
                              hipStream_t stream) {
  const float* x = (const float*)d_in[0];
  const float* y = (const float*)d_in[1];
  const float* W = (const float*)d_in[2];
  float* out = (float*)d_out;
  (void)in_sizes; (void)n_in; (void)out_size; (void)ws_size;

  unsigned short* WT = (unsigned short*)d_ws;   // 61440 * 2 B

  CGArg cga;
  compute_cg(cga.v);

  hipLaunchKernelGGL(wt_kernel, dim3(240), dim3(256), 0, stream, W, WT);
  hipLaunchKernelGGL(tp_kernel, dim3(2048), dim3(256), 0, stream, x, y, WT, out, cga);
}

// Round 6
// 56.749 us; speedup vs baseline: 1.5438x; 1.3443x over previous
//
#include <hip/hip_runtime.h>
#include <cmath>
#include <complex>
#include <algorithm>

// ---------------- compile-time path metadata ----------------
#define NPATH 15
constexpr int PL1[NPATH] = {0,0,0, 1,1,1,1,1,1, 2,2,2,2,2,2};
constexpr int PL2[NPATH] = {0,1,2, 0,1,1,1,2,2, 0,1,1,2,2,2};
constexpr int PL3[NPATH] = {0,1,2, 1,0,1,2,1,2, 2,1,2,0,1,2};
constexpr int CGOFF[NPATH] = {0,1,10,35,44,53,80,125,170,245,270,315,390,415,490};
constexpr int CGTOT = 615;
constexpr int YOFF[3] = {0,1,4};
constexpr int KKB[3]  = {0,1,4};  // acc k-base per l3

// general (non-delta) paths: 5:(1,1,1) 6:(1,1,2) 7:(1,2,1) 8:(1,2,2) 10:(2,1,1) 11:(2,1,2) 13:(2,2,1) 14:(2,2,2)
constexpr int GP[8] = {5,6,7,8,10,11,13,14};
constexpr int GB[8] = {0,9,24,33,48,63,88,103};   // cumsum of D1*D3: 9,15,9,15,15,25,15,25
constexpr int YGTOT = 137;                        // 128 general yc entries + 9 raw y
// s_yg layout: entry e, row n -> s_yg[e*16 + n]; raw y[j] at entry 128+j

struct CGArg { float v[CGTOT]; }; // alpha-folded real-basis CG (kernarg -> SGPR-resident constants)

// ---------------- host: exact port of reference CG construction ----------------
static double factd(int n){ double r=1.0; for(int i=2;i<=n;++i) r*=(double)i; return r; }

static double su2_cg(int j1,int m1,int j2,int m2,int j3,int m3){
  if (m3 != m1+m2) return 0.0;
  double c = (double)(2*j3+1) * factd(j1+j2-j3) * factd(j1-j2+j3) * factd(-j1+j2+j3)
             / factd(j1+j2+j3+1);
  c = std::sqrt(c);
  c *= std::sqrt(factd(j3+m3)*factd(j3-m3)*factd(j1-m1)*factd(j1+m1)*factd(j2-m2)*factd(j2+m2));
  double s = 0.0;
  int kmin = std::max(0, std::max(j2-j3-m1, j1-j3+m2));
  int kmax = std::min(j1+j2-j3, std::min(j1-m1, j2+m2));
  for (int k=kmin;k<=kmax;++k){
    double d = factd(k)*factd(j1+j2-j3-k)*factd(j1-m1-k)*factd(j2+m2-k)
             * factd(j3-j2+m1+k)*factd(j3-j1-m2+k);
    s += ((k&1)? -1.0 : 1.0)/d;
  }
  return c*s;
}

static void qmat(int l, std::complex<double>* q){
  int d = 2*l+1;
  for (int a=0;a<d*d;++a) q[a] = std::complex<double>(0.0,0.0);
  const double r2 = 1.0/std::sqrt(2.0);
  for (int m=-l; m<0; ++m){
    q[(l+m)*d + (l-m)] = std::complex<double>(r2, 0.0);
    q[(l+m)*d + (l+m)] = std::complex<double>(0.0, -r2);
  }
  q[l*d + l] = std::complex<double>(1.0,0.0);
  for (int m=1; m<=l; ++m){
    double sg = (m&1)? -1.0 : 1.0;
    q[(l+m)*d + (l+m)] = std::complex<double>(sg*r2, 0.0);
    q[(l+m)*d + (l-m)] = std::complex<double>(0.0, sg*r2);
  }
  std::complex<double> ph = (l==0)? std::complex<double>(1,0)
                        : (l==1)? std::complex<double>(0,-1)
                                : std::complex<double>(-1,0);   // (-i)^l
  for (int a=0;a<d*d;++a) q[a] *= ph;
}

static void compute_cg(float* outv){
  const int npaths_to[3] = {3,6,6};
  for (int p=0;p<NPATH;++p){
    int l1=PL1[p], l2=PL2[p], l3=PL3[p];
    int d1=2*l1+1, d2=2*l2+1, d3=2*l3+1;
    std::complex<double> C[5][5][5];
    for (int a=0;a<5;++a) for(int b=0;b<5;++b) for(int c=0;c<5;++c) C[a][b][c]=std::complex<double>(0,0);
    for (int m1=-l1;m1<=l1;++m1) for (int m2=-l2;m2<=l2;++m2){
      int m3=m1+m2;
      if (std::abs(m3)<=l3) C[l1+m1][l2+m2][l3+m3] = su2_cg(l1,m1,l2,m2,l3,m3);
    }
    std::complex<double> U1[25],U2[25],U3[25];
    qmat(l1,U1); qmat(l2,U2); qmat(l3,U3);
    double Cr[5][5][5]; double nrm=0.0;
    for (int a=0;a<d1;++a) for (int b=0;b<d2;++b) for (int c=0;c<d3;++c){
      std::complex<double> s(0,0);
      for (int i=0;i<d1;++i) for (int j=0;j<d2;++j) for (int k=0;k<d3;++k)
        s += U1[i*d1+a]*U2[j*d2+b]*std::conj(U3[k*d3+c])*C[i][j][k];
      Cr[a][b][c] = s.real();
      nrm += s.real()*s.real();
    }
    nrm = std::sqrt(nrm);
    double alpha = 1.0/std::sqrt(64.0*(double)npaths_to[l3]);
    float* o = outv + CGOFF[p];
    int idx=0;
    for (int a=0;a<d1;++a) for (int b=0;b<d2;++b) for (int c=0;c<d3;++c)
      o[idx++] = (float)(Cr[a][b][c]/nrm*alpha);
  }
}

// ---------------- device ----------------
typedef short bf16x8 __attribute__((ext_vector_type(8)));
typedef float f32x4 __attribute__((ext_vector_type(4)));

__device__ __forceinline__ unsigned cvtpk_bf16(float a, float b){
  unsigned r;
  asm("v_cvt_pk_bf16_f32 %0, %1, %2" : "=v"(r) : "v"(a), "v"(b));
  return r;   // lo16 = bf16(a), hi16 = bf16(b)
}

// A-fragment: lane (cl,q) holds A[row=cl][u=kt*32+q*8 ..+7]; XOR-swizzled 16B chunks (R2-verified)
__device__ __forceinline__ bf16x8 afrag(const unsigned short* s_xt, int plane, int kt, int row, int q){
  int c = (kt*4 + q) ^ (row & 7);
  return *reinterpret_cast<const bf16x8*>(s_xt + (plane*16 + row)*64 + c*8);
}
// B-fragment: lane (cl,q) holds B[u=kt*32+q*8..+7][w=wt*16+cl] from WT[p][w][u]
__device__ __forceinline__ bf16x8 wfrag(const unsigned short* WT, int p, int wt, int cl, int kt, int q){
  return *reinterpret_cast<const bf16x8*>(WT + p*4096 + (wt*16+cl)*64 + kt*32 + q*8);
}
// xT write of one packed u-quad (swizzle matches afrag)
__device__ __forceinline__ void xt_write_pk(unsigned short* s_xt, int plane, int n, int t16, uint2 pk){
  const int swz = (((t16>>1)^(n&7))<<3) + ((t16&1)<<2);
  *reinterpret_cast<uint2*>(s_xt + (plane*16 + n)*64 + swz) = pk;
}

// pack this thread's x registers (f32) into 9 packed bf16 u-quads (one per plane)
__device__ __forceinline__ void pack_x(const float4& r0, const float4* r1, const float4* r2, uint2* xpk){
  const float* f0 = reinterpret_cast<const float*>(&r0);   // 4:  x[t16*4+uu]
  const float* f1 = reinterpret_cast<const float*>(r1);    // 12: x[64 + (4t16+uu)*3 + i]
  const float* f2 = reinterpret_cast<const float*>(r2);    // 20: x[256 + (4t16+uu)*5 + i]
  xpk[0].x = cvtpk_bf16(f0[0], f0[1]);  xpk[0].y = cvtpk_bf16(f0[2], f0[3]);
  #pragma unroll
  for (int i=0;i<3;++i){
    xpk[1+i].x = cvtpk_bf16(f1[0*3+i], f1[1*3+i]);
    xpk[1+i].y = cvtpk_bf16(f1[2*3+i], f1[3*3+i]);
  }
  #pragma unroll
  for (int i=0;i<5;++i){
    xpk[4+i].x = cvtpk_bf16(f2[0*5+i], f2[1*5+i]);
    xpk[4+i].y = cvtpk_bf16(f2[2*5+i], f2[3*5+i]);
  }
}

// general path: per i: T = x-plane_i @ W_p (2 MFMA), immediately consumed vs yc (no T array)
template<int G,int L1,int L3>
__device__ __forceinline__ void gen_path(const unsigned short* s_xt, const bf16x8* a,
                                         bf16x8 b0, bf16x8 b1,
                                         const float* yg4, f32x4* acc){
  constexpr int D1=2*L1+1, D3=2*L3+1;
  const f32x4 z4 = {0.f,0.f,0.f,0.f};
  #pragma unroll
  for (int i=0;i<D1;++i){
    f32x4 T = __builtin_amdgcn_mfma_f32_16x16x32_bf16(a[2*i],   b0, z4, 0,0,0);
    T       = __builtin_amdgcn_mfma_f32_16x16x32_bf16(a[2*i+1], b1, T,  0,0,0);
    #pragma unroll
    for (int k=0;k<D3;++k){
      f32x4 yv = *reinterpret_cast<const f32x4*>(yg4 + (GB[G] + i*D3 + k)*16);
      acc[KKB[L3]+k] += T*yv;
    }
  }
}

__device__ __forceinline__ void epilogue(const f32x4* acc, float* __restrict__ out,
                                         int base, int wid, int cl, int q){
  const int wc = wid*16 + cl;
  #pragma unroll
  for (int r=0;r<4;++r){
    float* orow = out + (size_t)(base + q*4 + r)*576;
    orow[wc] = acc[0][r];
    #pragma unroll
    for (int k=0;k<3;++k) orow[64 + wc*3 + k]  = acc[1+k][r];
    #pragma unroll
    for (int k=0;k<5;++k) orow[256 + wc*5 + k] = acc[4+k][r];
  }
}

__global__ __launch_bounds__(256, 3)
void tp_kernel(const float* __restrict__ x, const float* __restrict__ y,
               const unsigned short* __restrict__ WT, float* __restrict__ out, CGArg cga)
{
  __shared__ __align__(16) unsigned short s_xt[9*16*64];  // 18432 B
  __shared__ __align__(16) float s_yg[YGTOT*16];          // 8768 B

  const int tid = threadIdx.x;
  const int n0 = blockIdx.x * 16;
  const int n_s = tid>>4, t16 = tid&15;
  const int lane = tid & 63, wid = tid >> 6;
  const int cl = lane & 15, q = lane >> 4;

  // ---- phase A: loads + staging + yc (single barrier after) ----
  const float* xb = x + (size_t)(n0 + n_s)*576;
  float4 r0 = *reinterpret_cast<const float4*>(xb + t16*4);
  float4 r1[3], r2[5];
  #pragma unroll
  for (int i=0;i<3;++i) r1[i] = *reinterpret_cast<const float4*>(xb + 64 + t16*12 + 4*i);
  #pragma unroll
  for (int i=0;i<5;++i) r2[i] = *reinterpret_cast<const float4*>(xb + 256 + t16*20 + 4*i);

  // each thread holds the full 9-vector y for row n = tid&15 (needed for its yc entries)
  float yl[9];
  {
    const float* yrow = y + (size_t)(n0 + t16)*9;
    #pragma unroll
    for (int j=0;j<9;++j) yl[j] = yrow[j];
  }

  uint2 xpk[9];
  pack_x(r0, r1, r2, xpk);
  #pragma unroll
  for (int pl=0; pl<9; ++pl) xt_write_pk(s_xt, pl, n_s, t16, xpk[pl]);

  // raw y -> s_yg entries 128..136 (one writer per row)
  if (tid < 16){
    #pragma unroll
    for (int j=0;j<9;++j) s_yg[(128+j)*16 + tid] = yl[j];
  }

  // general-path yc from register y (pre-barrier; each thread owns row tid&15)
  #pragma unroll
  for (int g=0; g<8; ++g){
    constexpr int GPp[8] = {5,6,7,8,10,11,13,14};
    const int p = GPp[g];
    const int d1=2*PL1[p]+1, d2=2*PL2[p]+1, d3=2*PL3[p]+1;
    const int cnt = d1*d3*16;
    for (int idx=tid; idx<cnt; idx+=256){
      int ik = idx >> 4;
      int i  = ik/d3;
      int k  = ik - i*d3;
      float s=0.f;
      for (int j=0;j<d2;++j)
        s += yl[YOFF[PL2[p]]+j]*cga.v[CGOFF[p]+(i*d2+j)*d3+k];
      s_yg[(GB[g]+ik)*16 + t16] = s;
    }
  }
  __syncthreads();

  // ---- phase B: MFMA + consume, no barriers ----
  const float* yg4 = s_yg + q*4;         // f32x4 over this lane-group's 4 rows
  #define YV(E) (*reinterpret_cast<const f32x4*>(yg4 + (E)*16))

  const f32x4 z4 = {0.f,0.f,0.f,0.f};
  f32x4 acc[9] = {z4,z4,z4,z4,z4,z4,z4,z4,z4};   // k: 0 | 1..3 | 4..8
  bf16x8 b0,b1,nb0,nb1;
  const f32x4 y0v = YV(128);

  #define LDB(P) { nb0 = wfrag(WT,P,wid,cl,0,q); nb1 = wfrag(WT,P,wid,cl,1,q); }
  #define ADV    { b0 = nb0; b1 = nb1; }

  b0 = wfrag(WT,0,wid,cl,0,q); b1 = wfrag(WT,0,wid,cl,1,q);

  // ===== l1=0 group =====
  {
    bf16x8 a0[2];
    #pragma unroll
    for (int kt=0;kt<2;++kt) a0[kt] = afrag(s_xt, 0, kt, cl, q);

    LDB(1);
    { // p0 (0,0,0): acc0 += c*y0*T
      f32x4 T = __builtin_amdgcn_mfma_f32_16x16x32_bf16(a0[0], b0, z4, 0,0,0);
      T       = __builtin_amdgcn_mfma_f32_16x16x32_bf16(a0[1], b1, T,  0,0,0);
      acc[0] += (cga.v[CGOFF[0]]*y0v)*T;
    } ADV;
    LDB(2);
    { // p1 (0,1,1): acc[1+k] += c*y[1+k]*T
      f32x4 T = __builtin_amdgcn_mfma_f32_16x16x32_bf16(a0[0], b0, z4, 0,0,0);
      T       = __builtin_amdgcn_mfma_f32_16x16x32_bf16(a0[1], b1, T,  0,0,0);
      #pragma unroll
      for (int k=0;k<3;++k) acc[1+k] += (cga.v[CGOFF[1]]*YV(129+k))*T;
    } ADV;
    LDB(3);
    { // p2 (0,2,2): acc[4+k] += c*y[4+k]*T
      f32x4 T = __builtin_amdgcn_mfma_f32_16x16x32_bf16(a0[0], b0, z4, 0,0,0);
      T       = __builtin_amdgcn_mfma_f32_16x16x32_bf16(a0[1], b1, T,  0,0,0);
      #pragma unroll
      for (int k=0;k<5;++k) acc[4+k] += (cga.v[CGOFF[2]]*YV(132+k))*T;
    } ADV;
  }

  // ===== l1=1 group =====
  {
    bf16x8 a1[6];
    #pragma unroll
    for (int i=0;i<3;++i)
      #pragma unroll
      for (int kt=0;kt<2;++kt) a1[2*i+kt] = afrag(s_xt, 1+i, kt, cl, q);

    LDB(4);
    { // p3 (1,0,1): acc[1+i] += (c*y0)*T_i
      f32x4 cy = cga.v[CGOFF[3]]*y0v;
      #pragma unroll
      for (int i=0;i<3;++i){
        f32x4 T = __builtin_amdgcn_mfma_f32_16x16x32_bf16(a1[2*i],   b0, z4, 0,0,0);
        T       = __builtin_amdgcn_mfma_f32_16x16x32_bf16(a1[2*i+1], b1, T,  0,0,0);
        acc[1+i] += cy*T;
      }
    } ADV;
    LDB(5);
    { // p4 (1,1,0): acc0 += c * sum_i y[1+i]*T_i
      f32x4 s = z4;
      #pragma unroll
      for (int i=0;i<3;++i){
        f32x4 T = __builtin_amdgcn_mfma_f32_16x16x32_bf16(a1[2*i],   b0, z4, 0,0,0);
        T       = __builtin_amdgcn_mfma_f32_16x16x32_bf16(a1[2*i+1], b1, T,  0,0,0);
        s += YV(129+i)*T;
      }
      acc[0] += s*cga.v[CGOFF[4]];
    } ADV;
    LDB(6);  gen_path<0,1,1>(s_xt, a1, b0, b1, yg4, acc); ADV;   // p5 (1,1,1)
    LDB(7);  gen_path<1,1,2>(s_xt, a1, b0, b1, yg4, acc); ADV;   // p6 (1,1,2)
    LDB(8);  gen_path<2,1,1>(s_xt, a1, b0, b1, yg4, acc); ADV;   // p7 (1,2,1)
    LDB(9);  gen_path<3,1,2>(s_xt, a1, b0, b1, yg4, acc); ADV;   // p8 (1,2,2)
  }

  // ===== l1=2 group =====
  {
    bf16x8 a2[10];
    #pragma unroll
    for (int i=0;i<5;++i)
      #pragma unroll
      for (int kt=0;kt<2;++kt) a2[2*i+kt] = afrag(s_xt, 4+i, kt, cl, q);

    LDB(10);
    { // p9 (2,0,2): acc[4+i] += (c*y0)*T_i
      f32x4 cy = cga.v[CGOFF[9]]*y0v;
      #pragma unroll
      for (int i=0;i<5;++i){
        f32x4 T = __builtin_amdgcn_mfma_f32_16x16x32_bf16(a2[2*i],   b0, z4, 0,0,0);
        T       = __builtin_amdgcn_mfma_f32_16x16x32_bf16(a2[2*i+1], b1, T,  0,0,0);
        acc[4+i] += cy*T;
      }
    } ADV;
    LDB(11); gen_path<4,2,1>(s_xt, a2, b0, b1, yg4, acc); ADV;   // p10 (2,1,1)
    LDB(12); gen_path<5,2,2>(s_xt, a2, b0, b1, yg4, acc); ADV;   // p11 (2,1,2)
    LDB(13);
    { // p12 (2,2,0): acc0 += c * sum_i y[4+i]*T_i
      f32x4 s = z4;
      #pragma unroll
      for (int i=0;i<5;++i){
        f32x4 T = __builtin_amdgcn_mfma_f32_16x16x32_bf16(a2[2*i],   b0, z4, 0,0,0);
        T       = __builtin_amdgcn_mfma_f32_16x16x32_bf16(a2[2*i+1], b1, T,  0,0,0);
        s += YV(132+i)*T;
      }
      acc[0] += s*cga.v[CGOFF[12]];
    } ADV;
    LDB(14); gen_path<6,2,1>(s_xt, a2, b0, b1, yg4, acc); ADV;   // p13 (2,2,1)
             gen_path<7,2,2>(s_xt, a2, b0, b1, yg4, acc);        // p14 (2,2,2)
  }
  #undef LDB
  #undef ADV
  #undef YV

  epilogue(acc, out, n0, wid, cl, q);
}

// W[p][u][w] (fp32) -> WT[p][w][u] (bf16, RNE) once per launch
__global__ void wt_kernel(const float* __restrict__ W, unsigned short* __restrict__ WT){
  int t = blockIdx.x*256 + threadIdx.x;      // 61440 total
  int p = t >> 12, r = t & 4095, w = r >> 6, u = r & 63;
  float f = W[(p<<12) + (u<<6) + w];
  unsigned fu = __builtin_bit_cast(unsigned, f);
  unsigned rr = (fu + 0x7FFFu + ((fu>>16)&1u)) >> 16;
  WT[t] = (unsigned short)rr;
}

// ---------------- launch ----------------
extern "C" void kernel_launch(void* const* d_in, const int* in_sizes, int n_in,
                              void* d_out, int out_size, void* d_ws, size_t ws_size,
                              hipStream_t stream) {
  const float* x = (const float*)d_in[0];
  const float* y = (const float*)d_in[1];
  const float* W = (const float*)d_in[2];
  float* out = (float*)d_out;
  (void)in_sizes; (void)n_in; (void)out_size; (void)ws_size;

  unsigned short* WT = (unsigned short*)d_ws;   // 61440 * 2 B

  CGArg cga;
  compute_cg(cga.v);

  hipLaunchKernelGGL(wt_kernel, dim3(240), dim3(256), 0, stream, W, WT);
  hipLaunchKernelGGL(tp_kernel, dim3(2048), dim3(256), 0, stream, x, y, WT, out, cga);
}